// Round 8
// baseline (264.476 us; speedup 1.0000x reference)
//
#include <hip/hip_runtime.h>
#include <stdint.h>

#define NN 50000
#define EE 800000
#define DD 128
#define RR 4
#define LL 3
#define NRSEG (NN*RR)                    // 200000 segments (dst*4 + etype)
#define NKB 20                           // K=640 in chunks of 32
#define NBK 196                          // bin buckets (seg>>10)
#define BKCAP 5120                       // fixed bucket region capacity (avg 4082, +16 sigma)
#define WCONV_T (LL*NKB*8*64)            // 30720 weight-conv threads

typedef _Float16 f16;
typedef _Float16 f16x8 __attribute__((ext_vector_type(8)));
typedef float f32x4 __attribute__((ext_vector_type(4)));

union U4H  { uint4 u; f16 h[8]; };

// ---------------- CSR build ----------------
// binA: 196 blocks x 4096 edges. LDS bucket histogram -> block-local counting sort into
// LDS staging -> coalesced bucket-contiguous writes to tmp. bcur[b] ends as bucket total.
__global__ __launch_bounds__(1024) void k_binA(const int* __restrict__ ei, const int* __restrict__ et,
                                               int* __restrict__ bcur, int2* __restrict__ tmp){
  __shared__ int bcnt[256];
  __shared__ int lbase[256];
  __shared__ int gbase[256];
  __shared__ int s[256];
  __shared__ int tot;
  __shared__ int2 stage[4096];
  int t = threadIdx.x;
  if(t < 256) bcnt[t] = 0;
  __syncthreads();

  int seg[4], src[4], bk[4], rk[4];
  #pragma unroll
  for(int j=0;j<4;j++){
    int e = blockIdx.x*4096 + j*1024 + t;
    if(e < EE){
      src[j] = ei[e];
      seg[j] = ei[EE+e]*RR + et[e];
      bk[j]  = seg[j] >> 10;
      rk[j]  = atomicAdd(&bcnt[bk[j]], 1);
    } else { seg[j] = -1; }
  }
  __syncthreads();

  if(t < 256) s[t] = bcnt[t];
  __syncthreads();
  for(int o=1;o<256;o<<=1){
    int x = (t<256 && t>=o) ? s[t-o] : 0;
    __syncthreads();
    if(t<256) s[t] += x;
    __syncthreads();
  }
  if(t < 256){
    lbase[t] = s[t] - bcnt[t];
    if(t == 255) tot = s[255];
    if(t < NBK && bcnt[t] > 0) gbase[t] = atomicAdd(&bcur[t], bcnt[t]);
  }
  __syncthreads();

  #pragma unroll
  for(int j=0;j<4;j++){
    if(seg[j] >= 0){
      int2 p; p.x = seg[j]; p.y = src[j];
      stage[lbase[bk[j]] + rk[j]] = p;
    }
  }
  __syncthreads();

  int T = tot;
  #pragma unroll
  for(int j=0;j<4;j++){
    int idx = j*1024 + t;
    if(idx < T){
      int2 p = stage[idx];
      int bb = p.x >> 10;
      tmp[(size_t)bb*BKCAP + gbase[bb] + (idx - lbase[bb])] = p;
    }
  }
}

// binB: one block per bucket. In-block prefix over bcur -> bucket base; per-segment LDS
// histogram + scan -> rowp slice; scatter ssrc via LDS cursors.
__global__ __launch_bounds__(1024) void k_binB(const int* __restrict__ bcur, const int2* __restrict__ tmp,
                                               int* __restrict__ rowp, int* __restrict__ ssrc){
  __shared__ int hist[1024];
  __shared__ int sc[1024];
  __shared__ int cur[1024];
  __shared__ int pre[256];
  int b = blockIdx.x, t = threadIdx.x;
  hist[t] = 0;
  if(t < 256) pre[t] = (t < b) ? bcur[t] : 0;
  __syncthreads();
  for(int o=128;o>0;o>>=1){ if(t<o) pre[t]+=pre[t+o]; __syncthreads(); }
  int gb = pre[0];
  __syncthreads();
  if(b == NBK-1){
    if(t < 256) pre[t] = (t < NBK) ? bcur[t] : 0;
    __syncthreads();
    for(int o=128;o>0;o>>=1){ if(t<o) pre[t]+=pre[t+o]; __syncthreads(); }
    if(t==0) rowp[NRSEG] = pre[0];
    __syncthreads();
  }
  int n = bcur[b];
  const int2* src = tmp + (size_t)b*BKCAP;
  for(int i = t; i < n; i += 1024) atomicAdd(&hist[src[i].x & 1023], 1);
  __syncthreads();
  sc[t] = hist[t]; __syncthreads();
  for(int o=1;o<1024;o<<=1){ int x=(t>=o)?sc[t-o]:0; __syncthreads(); sc[t]+=x; __syncthreads(); }
  int excl = gb + sc[t] - hist[t];
  cur[t] = excl;
  int idx = b*1024 + t;
  if(idx < NRSEG) rowp[idx] = excl;
  __syncthreads();
  for(int i = t; i < n; i += 1024){
    int2 p = src[i];
    int pos = atomicAdd(&cur[p.x & 1023], 1);
    ssrc[pos] = p.y;
  }
}

// ---------------- dtype converts (fused W + x) ----------------
__global__ __launch_bounds__(256) void k_convWX(const float* __restrict__ W, const float* __restrict__ root,
                                                f16* __restrict__ Wf,
                                                const float* __restrict__ x, f16* __restrict__ x16){
  int t = blockIdx.x*256 + threadIdx.x;
  if(t < WCONV_T){
    int lane = t & 63;
    int cb   = (t>>6) & 7;
    int kb   = (t>>9) % NKB;
    int l    = (t>>9) / NKB;
    int col  = cb*16 + (lane&15);
    int kbase= kb*32 + (lane>>4)*8;
    f16* dst = Wf + (size_t)t*8;
    #pragma unroll
    for(int e=0;e<8;e++){
      int k = kbase+e;
      float v = (k < 4*DD) ? W[(((size_t)l*RR + (k>>7))*DD + (k&127))*DD + col]
                           : root[((size_t)l*DD + (k-4*DD))*DD + col];
      dst[e] = (f16)v;
    }
  } else {
    int u = t - WCONV_T;
    if(u < NN*DD/8){
      const float4* xf = (const float4*)x + (size_t)u*2;
      float4 a = xf[0], b = xf[1];
      U4H o;
      o.h[0]=(f16)a.x; o.h[1]=(f16)a.y; o.h[2]=(f16)a.z; o.h[3]=(f16)a.w;
      o.h[4]=(f16)b.x; o.h[5]=(f16)b.y; o.h[6]=(f16)b.z; o.h[7]=(f16)b.w;
      ((uint4*)x16)[u] = o.u;
    }
  }
}

// ---------------- fused agg + GEMM + epilogue, one layer ----------------
// Block: 512 threads (8 waves), BM=64 rows. Phase 1: 32 quarter-wave groups aggregate
// the block's 256 segments into LDS At[64][512] (fp16, XOR-swizzled). Phase 2: GEMM
// K=640 (kb<16 from At, kb>=16 root from global x16), 8 waves = 4 row-tiles x 2 col-halves.
__device__ __forceinline__ void acc8(float a[8], uint4 v){
  U4H w; w.u = v;
  #pragma unroll
  for(int k=0;k<8;k++) a[k] += (float)w.h[k];
}

template<int LAST>
__global__ __launch_bounds__(512, 4) void k_fused(const f16* __restrict__ x16, const int* __restrict__ rowp,
                                                  const int* __restrict__ ssrc, const f16* __restrict__ Wf,
                                                  const float* __restrict__ bias, const float* __restrict__ gmm,
                                                  const float* __restrict__ bet,
                                                  f16* __restrict__ xnext, float* __restrict__ outf){
  __shared__ f16 At[64*512];        // 64 KB, swizzled: idx = row*512 + (col_h ^ ((row&7)<<3))
  __shared__ f16 Blds[2][4096];     // 16 KB
  int tid  = threadIdx.x;
  int lane = tid & 63, wid = tid >> 6;
  int blk  = blockIdx.x;
  int rbase = blk*64;

  // stage B kb=0 early (independent of gather)
  __builtin_amdgcn_global_load_lds(
      (const __attribute__((address_space(1))) void*)(Wf + wid*512 + lane*8),
      (__attribute__((address_space(3))) void*)(&Blds[0][wid*512]), 16, 0, 0);

  // ---- phase 1: gather 256 segments into At ----
  {
    int g = tid >> 4, l = tid & 15;
    const uint4* xl = (const uint4*)x16 + l;
    #pragma unroll 1
    for(int si=0; si<8; ++si){
      int seg_local = g*8 + si;
      int gseg = blk*256 + seg_local;
      int b=0, n=0;
      if(gseg < NRSEG){ b = rowp[gseg]; n = rowp[gseg+1] - b; }
      float acc[8];
      #pragma unroll
      for(int k=0;k<8;k++) acc[k]=0.f;
      for(int base=0; base<n; base+=4){
        int m = n - base;
        int i0 = b + base;
        int c0 = ssrc[i0];
        int c1 = (m>1) ? ssrc[i0+1] : c0;
        int c2 = (m>2) ? ssrc[i0+2] : c0;
        int c3 = (m>3) ? ssrc[i0+3] : c0;
        uint4 v0 = xl[(size_t)c0*16];
        uint4 v1 = xl[(size_t)c1*16];
        uint4 v2 = xl[(size_t)c2*16];
        uint4 v3 = xl[(size_t)c3*16];
        acc8(acc, v0);
        if(m>1) acc8(acc, v1);
        if(m>2) acc8(acc, v2);
        if(m>3) acc8(acc, v3);
      }
      float inv = 1.f/(float)max(n,1);
      U4H o;
      #pragma unroll
      for(int k=0;k<8;k++) o.h[k] = (f16)(acc[k]*inv);
      int row = seg_local >> 2;
      int col_h = (seg_local&3)*128 + l*8;
      *(uint4*)&At[row*512 + (col_h ^ ((row&7)<<3))] = o.u;
    }
  }

  // ---- phase 2: GEMM ----
  int fr = lane & 15, kg = lane >> 4;
  int wr = wid >> 1, wc = wid & 1;
  int arow = rbase + wr*16 + fr; if(arow >= NN) arow = NN-1;
  const f16* Xr = x16 + (size_t)arow*128 + kg*8;
  int rowA = wr*16 + fr;
  int abase = rowA*512, axor = (rowA&7)<<3;

  f32x4 acc[4];
  #pragma unroll
  for(int c=0;c<4;c++) acc[c] = (f32x4){0.f,0.f,0.f,0.f};

  for(int kb=0; kb<NKB; kb++){
    __syncthreads();                           // At ready (kb=0) / stage(kb) done, prev reads done
    if(kb+1 < NKB)
      __builtin_amdgcn_global_load_lds(
          (const __attribute__((address_space(1))) void*)(Wf + (size_t)(kb+1)*4096 + wid*512 + lane*8),
          (__attribute__((address_space(3))) void*)(&Blds[(kb+1)&1][wid*512]), 16, 0, 0);
    f16x8 a;
    if(kb < 16) a = *(const f16x8*)&At[abase + ((kb*32 + kg*8) ^ axor)];
    else        a = *(const f16x8*)(Xr + (kb-16)*32);
    const f16* bb = &Blds[kb&1][(wc*4)*512 + lane*8];
    #pragma unroll
    for(int cbl=0;cbl<4;cbl++){
      f16x8 b = *(const f16x8*)(bb + cbl*512);
      acc[cbl] = __builtin_amdgcn_mfma_f32_16x16x32_f16(a, b, acc[cbl], 0, 0, 0);
    }
  }

  // ---- epilogue: bias -> relu -> +residual -> LayerNorm (cross-half via LDS) ----
  // C/D: col = wc*64 + cbl*16 + fr, row = rbase + wr*16 + kg*4 + q
  float* sred = (float*)At;                    // overlay: [stat(2)][wc(2)][64]
  float bs[4];
  #pragma unroll
  for(int c=0;c<4;c++) bs[c] = bias[wc*64 + c*16 + fr];
  int g4 = kg*4;
  float vv[4][4];
  #pragma unroll
  for(int cbl=0;cbl<4;cbl++){
    int col = wc*64 + cbl*16 + fr;
    #pragma unroll
    for(int q=0;q<4;q++){
      float v = acc[cbl][q] + bs[cbl];
      v = v > 0.f ? v : 0.f;
      int row = rbase + wr*16 + g4 + q;
      float res = (row < NN) ? (float)x16[(size_t)row*128 + col] : 0.f;
      vv[cbl][q] = v + res;
    }
  }
  __syncthreads();                             // all At reads done before overlay write
  #pragma unroll
  for(int q=0;q<4;q++){
    float s1=0.f, s2=0.f;
    #pragma unroll
    for(int cbl=0;cbl<4;cbl++){ float v=vv[cbl][q]; s1+=v; s2+=v*v; }
    #pragma unroll
    for(int m=1;m<16;m<<=1){ s1 += __shfl_xor(s1,m,16); s2 += __shfl_xor(s2,m,16); }
    if(fr == 0){
      int rin = wr*16 + g4 + q;
      sred[(0*2+wc)*64 + rin] = s1;
      sred[(1*2+wc)*64 + rin] = s2;
    }
  }
  __syncthreads();
  #pragma unroll
  for(int q=0;q<4;q++){
    int rin = wr*16 + g4 + q;
    float S1 = sred[0*128 + rin] + sred[0*128 + 64 + rin];
    float S2 = sred[1*128 + rin] + sred[1*128 + 64 + rin];
    float mu  = S1*(1.f/128.f);
    float var = S2*(1.f/128.f) - mu*mu;
    float rs  = rsqrtf(var + 1e-5f);
    int row = rbase + wr*16 + g4 + q;
    if(row < NN){
      #pragma unroll
      for(int cbl=0;cbl<4;cbl++){
        int col = wc*64 + cbl*16 + fr;
        float y = (vv[cbl][q]-mu)*rs*gmm[col] + bet[col];
        if(LAST) outf[(size_t)row*128 + col] = y;
        else     xnext[(size_t)row*128 + col] = (f16)y;
      }
    }
  }
}

// ---------------- launch ----------------
extern "C" void kernel_launch(void* const* d_in, const int* in_sizes, int n_in,
                              void* d_out, int out_size, void* d_ws, size_t ws_size,
                              hipStream_t stream){
  const float* x    = (const float*)d_in[0];
  const int*   ei   = (const int*)d_in[1];
  const int*   et   = (const int*)d_in[2];
  const float* W    = (const float*)d_in[3];
  const float* root = (const float*)d_in[4];
  const float* bias = (const float*)d_in[5];
  const float* gmm  = (const float*)d_in[6];
  const float* bet  = (const float*)d_in[7];

  char* ws = (char*)d_ws;
  int*   bcur = (int*)(ws + 0);            // 784 B bucket totals (memset each call)
  int*   rowp = (int*)(ws + 2048);         // 800004 B
  int*   ssrc = (int*)(ws + 804096);       // 3.2 MB
  f16*   Wf   = (f16*)(ws + 4004096);      // 491520 B
  f16*   x16a = (f16*)(ws + 4495616);      // 12.8 MB
  f16*   x16b = (f16*)(ws + 17295616);     // 12.8 MB
  int2*  tmp  = (int2*)(ws + 30095616);    // 8.03 MB   (total ~38.1 MB)

  hipMemsetAsync(bcur, 0, 784, stream);
  k_binA  <<<NBK, 1024, 0, stream>>>(ei, et, bcur, tmp);
  k_binB  <<<NBK, 1024, 0, stream>>>(bcur, tmp, rowp, ssrc);
  k_convWX<<<(WCONV_T + NN*DD/8 + 255)/256, 256, 0, stream>>>(W, root, Wf, x, x16a);

  f16* xc = x16a; f16* xn = x16b;
  for(int l=0; l<LL; l++){
    if(l < LL-1)
      k_fused<0><<<(NN+63)/64, 512, 0, stream>>>(xc, rowp, ssrc, Wf + (size_t)l*81920,
                                                 bias+l*DD, gmm+l*DD, bet+l*DD, xn, nullptr);
    else
      k_fused<1><<<(NN+63)/64, 512, 0, stream>>>(xc, rowp, ssrc, Wf + (size_t)l*81920,
                                                 bias+l*DD, gmm+l*DD, bet+l*DD, nullptr, (float*)d_out);
    f16* t = xc; xc = xn; xn = t;
  }
}

// Round 9
// 222.031 us; speedup vs baseline: 1.1912x; 1.1912x over previous
//
#include <hip/hip_runtime.h>
#include <stdint.h>

#define NN 50000
#define EE 800000
#define DD 128
#define RR 4
#define LL 3
#define NRSEG (NN*RR)                    // 200000 segments (dst*4 + etype)
#define NKB 20                           // K=640 in chunks of 32
#define NBK 196                          // bin buckets (seg>>10)
#define BKCAP 5120                       // fixed bucket region capacity (avg 4082, +16 sigma)
#define WCONV_T (LL*NKB*8*64)            // 30720 weight-conv threads

typedef _Float16 f16;
typedef _Float16 f16x8 __attribute__((ext_vector_type(8)));
typedef float f32x4 __attribute__((ext_vector_type(4)));

union U4H  { uint4 u; f16 h[8]; };

// ---------------- dtype converts (fused W + x) + bcur zeroing ----------------
// Launched FIRST on the stream: block 0 zeroes the 196-int bucket cursor, so no
// hipMemsetAsync is needed (its fillBuffer dispatch cost ~39 us per replay).
__global__ __launch_bounds__(256) void k_convWX(const float* __restrict__ W, const float* __restrict__ root,
                                                f16* __restrict__ Wf,
                                                const float* __restrict__ x, f16* __restrict__ x16,
                                                int* __restrict__ bcur){
  int t = blockIdx.x*256 + threadIdx.x;
  if(blockIdx.x == 0 && threadIdx.x < NBK) bcur[threadIdx.x] = 0;
  if(t < WCONV_T){
    int lane = t & 63;
    int cb   = (t>>6) & 7;
    int kb   = (t>>9) % NKB;
    int l    = (t>>9) / NKB;
    int col  = cb*16 + (lane&15);
    int kbase= kb*32 + (lane>>4)*8;
    f16* dst = Wf + (size_t)t*8;
    #pragma unroll
    for(int e=0;e<8;e++){
      int k = kbase+e;
      float v = (k < 4*DD) ? W[(((size_t)l*RR + (k>>7))*DD + (k&127))*DD + col]
                           : root[((size_t)l*DD + (k-4*DD))*DD + col];
      dst[e] = (f16)v;
    }
  } else {
    int u = t - WCONV_T;
    if(u < NN*DD/8){
      const float4* xf = (const float4*)x + (size_t)u*2;
      float4 a = xf[0], b = xf[1];
      U4H o;
      o.h[0]=(f16)a.x; o.h[1]=(f16)a.y; o.h[2]=(f16)a.z; o.h[3]=(f16)a.w;
      o.h[4]=(f16)b.x; o.h[5]=(f16)b.y; o.h[6]=(f16)b.z; o.h[7]=(f16)b.w;
      ((uint4*)x16)[u] = o.u;
    }
  }
}

// ---------------- CSR build ----------------
// binA: 196 blocks x 4096 edges. LDS bucket histogram -> block-local counting sort into
// LDS staging -> coalesced bucket-contiguous writes to tmp. bcur[b] ends as bucket total.
__global__ __launch_bounds__(1024) void k_binA(const int* __restrict__ ei, const int* __restrict__ et,
                                               int* __restrict__ bcur, int2* __restrict__ tmp){
  __shared__ int bcnt[256];
  __shared__ int lbase[256];
  __shared__ int gbase[256];
  __shared__ int s[256];
  __shared__ int tot;
  __shared__ int2 stage[4096];
  int t = threadIdx.x;
  if(t < 256) bcnt[t] = 0;
  __syncthreads();

  int seg[4], src[4], bk[4], rk[4];
  #pragma unroll
  for(int j=0;j<4;j++){
    int e = blockIdx.x*4096 + j*1024 + t;
    if(e < EE){
      src[j] = ei[e];
      seg[j] = ei[EE+e]*RR + et[e];
      bk[j]  = seg[j] >> 10;
      rk[j]  = atomicAdd(&bcnt[bk[j]], 1);
    } else { seg[j] = -1; }
  }
  __syncthreads();

  if(t < 256) s[t] = bcnt[t];
  __syncthreads();
  for(int o=1;o<256;o<<=1){
    int x = (t<256 && t>=o) ? s[t-o] : 0;
    __syncthreads();
    if(t<256) s[t] += x;
    __syncthreads();
  }
  if(t < 256){
    lbase[t] = s[t] - bcnt[t];
    if(t == 255) tot = s[255];
    if(t < NBK && bcnt[t] > 0) gbase[t] = atomicAdd(&bcur[t], bcnt[t]);
  }
  __syncthreads();

  #pragma unroll
  for(int j=0;j<4;j++){
    if(seg[j] >= 0){
      int2 p; p.x = seg[j]; p.y = src[j];
      stage[lbase[bk[j]] + rk[j]] = p;
    }
  }
  __syncthreads();

  int T = tot;
  #pragma unroll
  for(int j=0;j<4;j++){
    int idx = j*1024 + t;
    if(idx < T){
      int2 p = stage[idx];
      int bb = p.x >> 10;
      tmp[(size_t)bb*BKCAP + gbase[bb] + (idx - lbase[bb])] = p;
    }
  }
}

// binB: one block per bucket. In-block prefix over bcur -> bucket base; per-segment LDS
// histogram + scan -> rowp slice; scatter ssrc via LDS cursors.
__global__ __launch_bounds__(1024) void k_binB(const int* __restrict__ bcur, const int2* __restrict__ tmp,
                                               int* __restrict__ rowp, int* __restrict__ ssrc){
  __shared__ int hist[1024];
  __shared__ int sc[1024];
  __shared__ int cur[1024];
  __shared__ int pre[256];
  int b = blockIdx.x, t = threadIdx.x;
  hist[t] = 0;
  if(t < 256) pre[t] = (t < b) ? bcur[t] : 0;
  __syncthreads();
  for(int o=128;o>0;o>>=1){ if(t<o) pre[t]+=pre[t+o]; __syncthreads(); }
  int gb = pre[0];
  __syncthreads();
  if(b == NBK-1){
    if(t < 256) pre[t] = (t < NBK) ? bcur[t] : 0;
    __syncthreads();
    for(int o=128;o>0;o>>=1){ if(t<o) pre[t]+=pre[t+o]; __syncthreads(); }
    if(t==0) rowp[NRSEG] = pre[0];
    __syncthreads();
  }
  int n = bcur[b];
  const int2* src = tmp + (size_t)b*BKCAP;
  for(int i = t; i < n; i += 1024) atomicAdd(&hist[src[i].x & 1023], 1);
  __syncthreads();
  sc[t] = hist[t]; __syncthreads();
  for(int o=1;o<1024;o<<=1){ int x=(t>=o)?sc[t-o]:0; __syncthreads(); sc[t]+=x; __syncthreads(); }
  int excl = gb + sc[t] - hist[t];
  cur[t] = excl;
  int idx = b*1024 + t;
  if(idx < NRSEG) rowp[idx] = excl;
  __syncthreads();
  for(int i = t; i < n; i += 1024){
    int2 p = src[i];
    int pos = atomicAdd(&cur[p.x & 1023], 1);
    ssrc[pos] = p.y;
  }
}

// ---------------- aggregation: one 16-lane quarter-wave per (node,relation) segment ----------------
__device__ __forceinline__ void acc8(float a[8], uint4 v){
  U4H w; w.u = v;
  #pragma unroll
  for(int k=0;k<8;k++) a[k] += (float)w.h[k];
}

__global__ __launch_bounds__(256) void k_agg(const f16* __restrict__ x16, const int* __restrict__ rowp,
                                             const int* __restrict__ ssrc, f16* __restrict__ A16){
  int seg = blockIdx.x*16 + (threadIdx.x >> 4);      // one segment per 16-lane group
  int l   = threadIdx.x & 15;
  if(seg >= NRSEG) return;

  int b = rowp[seg], e = rowp[seg+1];
  int n = e - b;
  const uint4* xl = (const uint4*)x16 + l;           // lane's 16B slice of each row

  float acc[8];
  #pragma unroll
  for(int k=0;k<8;k++) acc[k] = 0.f;

  // 4 independent gathers in flight per iteration (mean degree = 4)
  for(int base=0; base<n; base+=4){
    int m = n - base;
    int i0 = b + base;
    int c0 = ssrc[i0];
    int c1 = (m>1) ? ssrc[i0+1] : c0;
    int c2 = (m>2) ? ssrc[i0+2] : c0;
    int c3 = (m>3) ? ssrc[i0+3] : c0;
    uint4 v0 = xl[(size_t)c0*16];
    uint4 v1 = xl[(size_t)c1*16];
    uint4 v2 = xl[(size_t)c2*16];
    uint4 v3 = xl[(size_t)c3*16];
    acc8(acc, v0);
    if(m>1) acc8(acc, v1);
    if(m>2) acc8(acc, v2);
    if(m>3) acc8(acc, v3);
  }

  float inv = 1.f/(float)max(n,1);
  U4H o;
  #pragma unroll
  for(int k=0;k<8;k++) o.h[k] = (f16)(acc[k]*inv);
  ((uint4*)A16)[(size_t)seg*16 + l] = o.u;
}

// ---------------- GEMM (M=NN, K=640, N=128) + fused epilogue ----------------
// Block = 256 threads (4 waves), BM=128 rows; wave owns 32 rows x 128 cols.
__device__ __forceinline__ void stageB(const f16* __restrict__ Wf, f16* lds, int kb, int wid, int lane){
  const f16* src = Wf + (size_t)kb*4096;
  #pragma unroll
  for(int j=wid;j<8;j+=4){
    __builtin_amdgcn_global_load_lds((const __attribute__((address_space(1))) void*)(src + j*512 + lane*8),
                                     (__attribute__((address_space(3))) void*)(lds + j*512), 16, 0, 0);
  }
}

template<int LAST>
__global__ __launch_bounds__(256) void k_gemm(const f16* __restrict__ A16, const f16* __restrict__ x16,
                                              const f16* __restrict__ Wf,
                                              const float* __restrict__ bias, const float* __restrict__ gmm,
                                              const float* __restrict__ bet,
                                              f16* __restrict__ xnext, float* __restrict__ outf){
  __shared__ f16 Blds[2][4096];   // [buf][cb*512 + lane*8 + e]
  int tid  = threadIdx.x;
  int lane = tid & 63, wid = tid >> 6;
  int rbase = blockIdx.x*128 + wid*32;          // this wave's first row
  int fr = lane & 15, kg = lane >> 4;

  int arow0 = rbase + fr;       if(arow0 >= NN) arow0 = NN-1;
  int arow1 = rbase + 16 + fr;  if(arow1 >= NN) arow1 = NN-1;
  const f16* Ar0 = A16 + (size_t)arow0*512 + kg*8;
  const f16* Ar1 = A16 + (size_t)arow1*512 + kg*8;
  const f16* Xr0 = x16 + (size_t)arow0*128 + kg*8;
  const f16* Xr1 = x16 + (size_t)arow1*128 + kg*8;

  f32x4 acc[2][8];
  #pragma unroll
  for(int r=0;r<2;r++)
    #pragma unroll
    for(int c=0;c<8;c++) acc[r][c] = (f32x4){0.f,0.f,0.f,0.f};

  f16x8 a0, a1;
  a0 = *(const f16x8*)(Ar0); a1 = *(const f16x8*)(Ar1);
  stageB(Wf, &Blds[0][0], 0, wid, lane);

  for(int kb=0; kb<NKB; kb++){
    __syncthreads();                                   // stage(kb) done, prev reads done
    if(kb+1 < NKB) stageB(Wf, &Blds[(kb+1)&1][0], kb+1, wid, lane);
    f16x8 na0 = a0, na1 = a1;
    if(kb+1 < NKB){
      if(kb+1 < 16){ na0 = *(const f16x8*)(Ar0 + (kb+1)*32); na1 = *(const f16x8*)(Ar1 + (kb+1)*32); }
      else         { na0 = *(const f16x8*)(Xr0 + (kb+1-16)*32); na1 = *(const f16x8*)(Xr1 + (kb+1-16)*32); }
    }
    const f16* bb = &Blds[kb&1][lane*8];
    #pragma unroll
    for(int cb=0;cb<8;cb++){
      f16x8 b = *(const f16x8*)(bb + cb*512);
      acc[0][cb] = __builtin_amdgcn_mfma_f32_16x16x32_f16(a0, b, acc[0][cb], 0, 0, 0);
      acc[1][cb] = __builtin_amdgcn_mfma_f32_16x16x32_f16(a1, b, acc[1][cb], 0, 0, 0);
    }
    a0 = na0; a1 = na1;
  }

  // epilogue: bias -> relu -> +residual -> LayerNorm  (C/D: col=lane&15, row=(lane>>4)*4+q)
  float bs[8];
  #pragma unroll
  for(int cb=0;cb<8;cb++) bs[cb] = bias[cb*16 + fr];
  int g4 = kg*4;
  #pragma unroll
  for(int rh=0; rh<2; rh++){
    float vv[8][4];
    #pragma unroll
    for(int cb=0;cb<8;cb++){
      int col = cb*16 + fr;
      #pragma unroll
      for(int q=0;q<4;q++){
        float v = acc[rh][cb][q] + bs[cb];
        v = v > 0.f ? v : 0.f;
        int row = rbase + rh*16 + g4 + q;
        float res = (row < NN) ? (float)x16[(size_t)row*128 + col] : 0.f;
        vv[cb][q] = v + res;
      }
    }
    #pragma unroll
    for(int q=0;q<4;q++){
      float s1=0.f, s2=0.f;
      #pragma unroll
      for(int cb=0;cb<8;cb++){ float v=vv[cb][q]; s1+=v; s2+=v*v; }
      #pragma unroll
      for(int m=1;m<16;m<<=1){ s1 += __shfl_xor(s1,m,16); s2 += __shfl_xor(s2,m,16); }
      float mu  = s1*(1.f/128.f);
      float var = s2*(1.f/128.f) - mu*mu;
      float rs  = rsqrtf(var + 1e-5f);
      int row = rbase + rh*16 + g4 + q;
      if(row < NN){
        #pragma unroll
        for(int cb=0;cb<8;cb++){
          int col = cb*16 + fr;
          float y = (vv[cb][q]-mu)*rs*gmm[col] + bet[col];
          if(LAST) outf[(size_t)row*128 + col] = y;
          else     xnext[(size_t)row*128 + col] = (f16)y;
        }
      }
    }
  }
}

// ---------------- launch ----------------
extern "C" void kernel_launch(void* const* d_in, const int* in_sizes, int n_in,
                              void* d_out, int out_size, void* d_ws, size_t ws_size,
                              hipStream_t stream){
  const float* x    = (const float*)d_in[0];
  const int*   ei   = (const int*)d_in[1];
  const int*   et   = (const int*)d_in[2];
  const float* W    = (const float*)d_in[3];
  const float* root = (const float*)d_in[4];
  const float* bias = (const float*)d_in[5];
  const float* gmm  = (const float*)d_in[6];
  const float* bet  = (const float*)d_in[7];

  char* ws = (char*)d_ws;
  int*   bcur = (int*)(ws + 0);            // 784 B bucket totals (zeroed by k_convWX block 0)
  int*   rowp = (int*)(ws + 2048);         // 800004 B
  int*   ssrc = (int*)(ws + 804096);       // 3.2 MB
  f16*   Wf   = (f16*)(ws + 4004096);      // 491520 B
  f16*   x16a = (f16*)(ws + 4495616);      // 12.8 MB
  f16*   x16b = (f16*)(ws + 17295616);     // 12.8 MB
  f16*   A16  = (f16*)(ws + 30095616);     // 51.2 MB
  int2*  tmp  = (int2*)(ws + 81295616);    // 8.03 MB  (total ~89.3 MB)

  // convWX first: zeroes bcur (stream-serialized before binA) + converts W and x
  k_convWX<<<(WCONV_T + NN*DD/8 + 255)/256, 256, 0, stream>>>(W, root, Wf, x, x16a, bcur);
  k_binA  <<<NBK, 1024, 0, stream>>>(ei, et, bcur, tmp);
  k_binB  <<<NBK, 1024, 0, stream>>>(bcur, tmp, rowp, ssrc);

  f16* xc = x16a; f16* xn = x16b;
  for(int l=0; l<LL; l++){
    k_agg<<<NRSEG/16, 256, 0, stream>>>(xc, rowp, ssrc, A16);
    if(l < LL-1)
      k_gemm<0><<<(NN+127)/128, 256, 0, stream>>>(A16, xc, Wf + (size_t)l*81920,
                                                  bias+l*DD, gmm+l*DD, bet+l*DD, xn, nullptr);
    else
      k_gemm<1><<<(NN+127)/128, 256, 0, stream>>>(A16, xc, Wf + (size_t)l*81920,
                                                  bias+l*DD, gmm+l*DD, bet+l*DD, nullptr, (float*)d_out);
    f16* t = xc; xc = xn; xn = t;
  }
}